// Round 1
// 164864.294 us; speedup vs baseline: 2.7399x; 2.7399x over previous
//
#include <hip/hip_runtime.h>
#include <math.h>

#define LL 2
#define BB 64
#define TT 512
#define II 512
#define HH 512
#define PP 256
#define OO 512
#define IH 1024

#define NG   8                 // groups; blockIdx%8 -> same XCD (perf heuristic only)
#define BPG  32                // blocks per group
#define RPG  8                 // batch rows per group
#define NBLK (NG*BPG)          // 256 blocks, 1 per CU (LDS-limited) -> co-resident
#define NTHR 512               // 8 waves/block
#define TPG  (BPG*NTHR)        // 16384 threads per group

// ---- all mutable state in __device__ globals (fp64 recurrence) ----
__device__ __align__(256) double g_h0[BB*HH];
__device__ __align__(256) double g_h1[BB*HH];
__device__ __align__(256) double g_m0[BB*PP];
__device__ __align__(256) double g_m1[BB*PP];
__device__ __align__(256) double g_u0[BB*HH];
__device__ __align__(256) double g_u1[BB*HH];
__device__ __align__(256) double g_rh0[BB*HH];
__device__ __align__(256) double g_rh1[BB*HH];
__device__ __align__(256) double g_hc0[BB*HH];
__device__ __align__(256) double g_hc1[BB*HH];
__device__ __align__(256) double g_mo0[BB*PP];
__device__ __align__(256) double g_mo1[BB*PP];
__device__ __align__(256) double g_hist[(long)BB*TT*HH];   // fp64 h_mem1 history
__device__ unsigned g_sync[NG*32];                          // per-group cnt/gen, 128B apart

struct KP {
  const float *x,*Wr,*br,*Wu,*bu,*Wn,*bn,*Wmr,*bmr,*Wmw,*bmw,*Wmu,*bmu,
              *Wmh,*bmh,*Wd,*bd,*Ws,*bs,*Wout,*bout,*dop,*ser;
  float* out;
};

__device__ inline double sigd(double x){ return 1.0/(1.0+exp(-x)); }

// fp64-accum dot, A in LDS (double), W fp32 in global
template<int K>
__device__ inline double dotLD(const double* a, const float* w){
  double s0=0,s1=0,s2=0,s3=0;
  #pragma unroll 4
  for (int k=0;k<K;k+=4){
    double2 a0 = *(const double2*)(a+k);
    double2 a1 = *(const double2*)(a+k+2);
    float4 wv = *(const float4*)(w+k);
    s0 = fma(a0.x,(double)wv.x,s0);
    s1 = fma(a0.y,(double)wv.y,s1);
    s2 = fma(a1.x,(double)wv.z,s2);
    s3 = fma(a1.y,(double)wv.w,s3);
  }
  return (s0+s1)+(s2+s3);
}

// 4 dots sharing one LDS A stream (write-gate quad)
template<int K>
__device__ inline void dot4LD(const double* a, const float* w0,const float* w1,
    const float* w2,const float* w3,double& o0,double& o1,double& o2,double& o3){
  double s0=0,s1=0,s2=0,s3=0;
  #pragma unroll 2
  for (int k=0;k<K;k+=2){
    double2 av = *(const double2*)(a+k);
    float2 b0=*(const float2*)(w0+k), b1=*(const float2*)(w1+k),
           b2=*(const float2*)(w2+k), b3=*(const float2*)(w3+k);
    s0 = fma(av.x,(double)b0.x,fma(av.y,(double)b0.y,s0));
    s1 = fma(av.x,(double)b1.x,fma(av.y,(double)b1.y,s1));
    s2 = fma(av.x,(double)b2.x,fma(av.y,(double)b2.y,s2));
    s3 = fma(av.x,(double)b3.x,fma(av.y,(double)b3.y,s3));
  }
  o0=s0;o1=s1;o2=s2;o3=s3;
}

// fp64-accum dot, A fp64 in global (out_gemm)
__device__ inline double dotD(const double* a, const float* w, int K){
  double s0=0,s1=0,s2=0,s3=0;
  #pragma unroll 4
  for (int k=0;k<K;k+=4){
    double2 a0 = *(const double2*)(a+k);
    double2 a1 = *(const double2*)(a+k+2);
    float4 wv = *(const float4*)(w+k);
    s0 = fma(a0.x,(double)wv.x,s0);
    s1 = fma(a0.y,(double)wv.y,s1);
    s2 = fma(a1.x,(double)wv.z,s2);
    s3 = fma(a1.y,(double)wv.w,s3);
  }
  return (s0+s1)+(s2+s3);
}

// group-local barrier: 32 blocks, sense-reversing, device-scope (proven pattern)
__device__ inline void gbar(int g){
  __syncthreads();
  if (threadIdx.x == 0){
    __threadfence();
    unsigned* cnt = &g_sync[g*32];
    unsigned* gen = &g_sync[g*32+16];
    unsigned ge  = __hip_atomic_load(gen, __ATOMIC_RELAXED, __HIP_MEMORY_SCOPE_AGENT);
    unsigned old = __hip_atomic_fetch_add(cnt, 1u, __ATOMIC_ACQ_REL, __HIP_MEMORY_SCOPE_AGENT);
    if (old == BPG-1){
      __hip_atomic_store(cnt, 0u, __ATOMIC_RELAXED, __HIP_MEMORY_SCOPE_AGENT);
      __hip_atomic_fetch_add(gen, 1u, __ATOMIC_RELEASE, __HIP_MEMORY_SCOPE_AGENT);
    } else {
      while (__hip_atomic_load(gen, __ATOMIC_ACQUIRE, __HIP_MEMORY_SCOPE_AGENT) == ge)
        __builtin_amdgcn_s_sleep(1);
    }
    __threadfence();
  }
  __syncthreads();
}

__global__ void __launch_bounds__(NTHR) rnn_kernel(KP p)
{
  const int tid  = threadIdx.x;
  const int g    = blockIdx.x & (NG-1);
  const int bg   = blockIdx.x >> 3;            // 0..31 within group
  const int gtid = bg*NTHR + tid;              // 0..16383 within group
  const int r0   = g*RPG;                      // first global batch row of group

  // LDS: activation staging (rows padded to 514/258 dbl -> rows hit distinct banks)
  __shared__ double sX[RPG][514];   // x_t rows, widened to fp64
  __shared__ double sA[RPG][514];   // h0, later hm0
  __shared__ double sB[RPG][514];   // rh / hc
  __shared__ double sC[RPG][514];   // h1 (= h_mem1(t-1))
  __shared__ double sM[RPG][258];   // mem_out rows

  double* h0g = g_h0 + r0*HH;  double* h1g = g_h1 + r0*HH;
  double* m0g = g_m0 + r0*PP;  double* m1g = g_m1 + r0*PP;
  double* u0g = g_u0 + r0*HH;  double* u1g = g_u1 + r0*HH;
  double* rh0g= g_rh0+ r0*HH;  double* rh1g= g_rh1+ r0*HH;
  double* hc0g= g_hc0+ r0*HH;  double* hc1g= g_hc1+ r0*HH;
  double* mo0g= g_mo0+ r0*PP;  double* mo1g= g_mo1+ r0*PP;

  // zero init own rows only (groups touch disjoint state)
  for (int i = gtid; i < RPG*HH; i += TPG){ h0g[i]=0.0; h1g[i]=0.0; }
  for (int i = gtid; i < RPG*PP; i += TPG){ m0g[i]=0.0; m1g[i]=0.0; }
  gbar(g);

  const float *Wr0=p.Wr,  *Wr1=p.Wr + (long)HH*IH;
  const float *Wu0=p.Wu,  *Wu1=p.Wu + (long)HH*IH;
  const float *Wn0=p.Wn,  *Wn1=p.Wn + (long)HH*IH;
  const float *br0=p.br,  *br1=p.br+HH;
  const float *bu0=p.bu,  *bu1=p.bu+HH;
  const float *bn0=p.bn,  *bn1=p.bn+HH;
  const float *Wmr0=p.Wmr, *Wmr1=p.Wmr+(long)PP*HH;
  const float *bmr0=p.bmr, *bmr1=p.bmr+PP;
  const float *Wmw0=p.Wmw, *Wmw1=p.Wmw+(long)PP*HH;
  const float *bmw0=p.bmw, *bmw1=p.bmw+PP;
  const float *Wmu0=p.Wmu, *Wmu1=p.Wmu+(long)PP*HH;
  const float *bmu0=p.bmu, *bmu1=p.bmu+PP;
  const float *Wd0=p.Wd,   *Wd1=p.Wd+(long)PP*HH;
  const float *bd0=p.bd,   *bd1=p.bd+PP;
  const float *Ws0=p.Ws,   *Ws1=p.Ws+(long)PP*HH;
  const float *bs0=p.bs,   *bs1=p.bs+PP;
  const float *Wmh0=p.Wmh, *Wmh1=p.Wmh+(long)HH*PP;
  const float *bmh0=p.bmh, *bmh1=p.bmh+HH;
  const double dopa = (double)p.dop[0];
  const double sero = (double)p.ser[0];

  // ---- LDS loaders (group slices are row-contiguous in global) ----
  auto loadD512 = [&](double dst[RPG][514], const double* src){
    for (int i = tid; i < RPG*HH/2; i += NTHR){
      int r = i >> 8, c2 = (i & 255) << 1;
      double2 v = *(const double2*)(src + (i<<1));
      *(double2*)&dst[r][c2] = v;
    }
  };
  auto loadX = [&](const float* src){   // row stride TT*II
    for (int i = tid; i < RPG*II/4; i += NTHR){
      int r = i >> 7, c4 = (i & 127) << 2;
      float4 v = *(const float4*)(src + (long)r*TT*II + c4);
      sX[r][c4]   = (double)v.x;
      sX[r][c4+1] = (double)v.y;
      sX[r][c4+2] = (double)v.z;
      sX[r][c4+3] = (double)v.w;
    }
  };
  auto loadM256 = [&](const double* src){
    for (int i = tid; i < RPG*PP/2; i += NTHR){
      int r = i >> 7, c2 = (i & 127) << 1;
      double2 v = *(const double2*)(src + (i<<1));
      *(double2*)&sM[r][c2] = v;
    }
  };

  // ---- stages: split-K across lanes + shfl-xor reduce, ks0 lane writes ----
  // r,u gates: 8192 outs, s=2 (ks0: input part, ks1: hidden part)
  auto stage_ru = [&](const double (*A1)[514], const double (*Ah)[514],
                      const float* Wr_l, const float* Wu_l,
                      const float* br_l, const float* bu_l,
                      double* rhg, double* ug){
    int out = gtid >> 1, ks = gtid & 1;
    int row = out & 7, rest = out >> 3;
    int gate = rest >> 9, col = rest & 511;
    const float* wrow = (gate ? Wu_l : Wr_l) + (long)col*IH + (ks ? II : 0);
    const double* a = ks ? &Ah[row][0] : &A1[row][0];
    double part = dotLD<512>(a, wrow);
    part += __shfl_xor(part, 1);
    if (!ks){
      double s = sigd(part + (double)(gate ? bu_l : br_l)[col]);
      int idx = row*HH + col;
      if (gate) ug[idx] = s; else rhg[idx] = s * Ah[row][col];
    }
  };
  // n + h_cand: 4096 outs, s=2, on threads gtid < TPG/2
  auto stage_n = [&](const double (*A1)[514], const double (*Ar)[514], const double (*Ah)[514],
                     const float* Wn_l, const float* bn_l, const double* ug, double* hcg){
    int out = gtid >> 1, ks = gtid & 1;
    int row = out & 7, col = out >> 3;
    const float* wrow = Wn_l + (long)col*IH + (ks ? II : 0);
    const double* a = ks ? &Ar[row][0] : &A1[row][0];
    double part = dotLD<512>(a, wrow);
    part += __shfl_xor(part, 1);
    if (!ks){
      double n = tanh(part + (double)bn_l[col]);
      int idx = row*HH + col;
      double u = ug[idx];
      hcg[idx] = (1.0 - u)*Ah[row][col] + u*n;
    }
  };
  // fused write-gate quad (mw,mu,d,s share one A stream), s=4 over K=512,
  // on threads gtid >= TPG/2
  auto stage_mg = [&](const double (*A)[514],
                      const float* Wmw_l,const float* Wmu_l,const float* Wd_l,const float* Ws_l,
                      const float* bmw_l,const float* bmu_l,const float* bd_l,const float* bs_l,
                      double* mg){
    int idx2 = gtid - (TPG/2);
    int task = idx2 >> 2, ks = idx2 & 3;
    int row = task & 7, pcol = task >> 3;
    long wr = (long)pcol*HH + ks*128;
    const double* a = &A[row][ks*128];
    double p0,p1,p2,p3;
    dot4LD<128>(a, Wmw_l+wr, Wmu_l+wr, Wd_l+wr, Ws_l+wr, p0,p1,p2,p3);
    p0 += __shfl_xor(p0,1); p0 += __shfl_xor(p0,2);
    p1 += __shfl_xor(p1,1); p1 += __shfl_xor(p1,2);
    p2 += __shfl_xor(p2,1); p2 += __shfl_xor(p2,2);
    p3 += __shfl_xor(p3,1); p3 += __shfl_xor(p3,2);
    if (!ks){
      double wg = sigd(p0 + (double)bmw_l[pcol]);
      double nm = tanh(p1 + (double)bmu_l[pcol]);
      double dp = sigd((p2 + (double)bd_l[pcol])*dopa);
      double sr = sigd((p3 + (double)bs_l[pcol])*sero);
      double w = wg*dp*(1.0 - sr);
      int mi = row*PP + pcol;
      mg[mi] = (1.0 - w)*mg[mi] + w*nm;
    }
  };
  // read gate: 2048 outs, s=8 over K=512
  auto stage_rg = [&](const double (*A)[514], const float* Wmr_l, const float* bmr_l,
                      const double* mgl, double* mog){
    int out = gtid >> 3, ks = gtid & 7;
    int row = out & 7, pcol = out >> 3;
    const float* wrow = Wmr_l + (long)pcol*HH + ks*64;
    double part = dotLD<64>(&A[row][ks*64], wrow);
    part += __shfl_xor(part,1);
    part += __shfl_xor(part,2);
    part += __shfl_xor(part,4);
    if (!ks){
      int mi = row*PP + pcol;
      mog[mi] = sigd(part + (double)bmr_l[pcol]) * mgl[mi];
    }
  };
  // h_mem: 4096 outs, s=4 over K=256 (A = sM)
  auto stage_hm = [&](const float* Wmh_l, const float* bmh_l, const double (*Ahc)[514],
                      double* hg, bool wr_hist, int t){
    int out = gtid >> 2, ks = gtid & 3;
    int row = out & 7, col = out >> 3;
    const float* wrow = Wmh_l + (long)col*PP + ks*64;
    double part = dotLD<64>(&sM[row][ks*64], wrow);
    part += __shfl_xor(part,1);
    part += __shfl_xor(part,2);
    if (!ks){
      int idx = row*HH + col;
      double hm = part + (double)bmh_l[col] + Ahc[row][col];
      hg[idx] = hm;
      if (wr_hist) g_hist[((long)(r0+row)*TT + t)*HH + col] = hm;
    }
  };

  for (int t=0; t<TT; ++t){
    // S1: r0,u0 from [x_t, h0]; also stage h1(t-1) into sC for S2-mg1/S5/S6
    loadX(p.x + (long)r0*TT*II + (long)t*II);
    loadD512(sA, h0g);
    loadD512(sC, h1g);
    __syncthreads();
    stage_ru(sX, sA, Wr0,Wu0,br0,bu0, rh0g,u0g);
    gbar(g);
    // S2: n0 -> h_cand0 || deferred m1 update for t-1 (A = sC)
    loadD512(sB, rh0g);
    __syncthreads();
    if (gtid < TPG/2)
      stage_n(sX, sB, sA, Wn0, bn0, u0g, hc0g);
    else if (t > 0)
      stage_mg(sC, Wmw1,Wmu1,Wd1,Ws1, bmw1,bmu1,bd1,bs1, m1g);
    gbar(g);
    // S3: read gate 0 -> mem_out0
    loadD512(sB, hc0g);
    __syncthreads();
    stage_rg(sB, Wmr0, bmr0, m0g, mo0g);
    gbar(g);
    // S4: h_mem0 (becomes h0 and layer-1 input)
    loadM256(mo0g);
    __syncthreads();
    stage_hm(Wmh0, bmh0, sB, h0g, false, t);
    gbar(g);
    // S5: r1,u1 from [h_mem0, h1]
    loadD512(sA, h0g);           // hm0(t)
    __syncthreads();
    stage_ru(sA, sC, Wr1,Wu1,br1,bu1, rh1g,u1g);
    gbar(g);
    // S6: n1 -> h_cand1 || m0 update (A = sA = hm0(t))
    loadD512(sB, rh1g);
    __syncthreads();
    if (gtid < TPG/2)
      stage_n(sA, sB, sC, Wn1, bn1, u1g, hc1g);
    else
      stage_mg(sA, Wmw0,Wmu0,Wd0,Ws0, bmw0,bmu0,bd0,bs0, m0g);
    gbar(g);
    // S7: read gate 1 -> mem_out1
    loadD512(sB, hc1g);
    __syncthreads();
    stage_rg(sB, Wmr1, bmr1, m1g, mo1g);
    gbar(g);
    // S8: h_mem1 (becomes h1; fp64 history for deferred out projection)
    loadM256(mo1g);
    __syncthreads();
    stage_hm(Wmh1, bmh1, sB, h1g, true, t);
    gbar(g);
  }

  // flush deferred m1 update for t = TT-1
  loadD512(sC, h1g);
  __syncthreads();
  if (gtid >= TPG/2)
    stage_mg(sC, Wmw1,Wmu1,Wd1,Ws1, bmw1,bmu1,bd1,bs1, m1g);
  gbar(g);

  // finals appended after outputs, FP32: h_final [2,B,H], m_final [2,B,P]
  const long obase = (long)BB*TT*OO;
  for (int i = gtid; i < RPG*HH; i += TPG){
    int row = i >> 9, col = i & 511;
    long o = (long)(r0+row)*HH + col;
    p.out[obase + o] = (float)h0g[i];
    p.out[obase + (long)BB*HH + o] = (float)h1g[i];
  }
  for (int i = gtid; i < RPG*PP; i += TPG){
    int row = i >> 8, col = i & 255;
    long o = (long)(r0+row)*PP + col;
    p.out[obase + 2L*BB*HH + o] = (float)m0g[i];
    p.out[obase + 2L*BB*HH + (long)BB*PP + o] = (float)m1g[i];
  }
}

// outputs[b,t,:] = Wout @ h_mem1[b,t,:] + bout  (fp64 accum, FP32 store)
__global__ void __launch_bounds__(256) out_gemm(const float* Wout, const float* bout, float* out)
{
  int w = blockIdx.x*4 + (threadIdx.x>>6);
  int lane = threadIdx.x & 63;
  const int NW = 2048*4;
  for (int job = w; job < (BB*TT/16)*(OO/4); job += NW){
    int r   = (job>>7)*16 + (lane&15);        // r = b*T + t
    int col = (job&127)*4 + (lane>>4);
    double acc = dotD(g_hist + (long)r*HH, Wout + (long)col*HH, HH);
    out[(long)r*OO + col] = (float)(acc + (double)bout[col]);
  }
}

extern "C" void kernel_launch(void* const* d_in, const int* in_sizes, int n_in,
                              void* d_out, int out_size, void* d_ws, size_t ws_size,
                              hipStream_t stream)
{
  KP p;
  p.x   = (const float*)d_in[0];
  p.Wr  = (const float*)d_in[1];  p.br  = (const float*)d_in[2];
  p.Wu  = (const float*)d_in[3];  p.bu  = (const float*)d_in[4];
  p.Wn  = (const float*)d_in[5];  p.bn  = (const float*)d_in[6];
  p.Wmr = (const float*)d_in[7];  p.bmr = (const float*)d_in[8];
  p.Wmw = (const float*)d_in[9];  p.bmw = (const float*)d_in[10];
  p.Wmu = (const float*)d_in[11]; p.bmu = (const float*)d_in[12];
  p.Wmh = (const float*)d_in[13]; p.bmh = (const float*)d_in[14];
  p.Wd  = (const float*)d_in[15]; p.bd  = (const float*)d_in[16];
  p.Ws  = (const float*)d_in[17]; p.bs  = (const float*)d_in[18];
  p.Wout= (const float*)d_in[19]; p.bout= (const float*)d_in[20];
  p.dop = (const float*)d_in[21]; p.ser = (const float*)d_in[22];
  p.out = (float*)d_out;

  rnn_kernel<<<dim3(NBLK), dim3(NTHR), 0, stream>>>(p);
  out_gemm<<<dim3(2048), dim3(256), 0, stream>>>(p.Wout, p.bout, p.out);
}

// Round 2
// 138438.733 us; speedup vs baseline: 3.2628x; 1.1909x over previous
//
#include <hip/hip_runtime.h>
#include <math.h>

#define LL 2
#define BB 64
#define TT 512
#define II 512
#define HH 512
#define PP 256
#define OO 512
#define IH 1024

#define NG   8                 // groups; blockIdx%8 -> same XCD
#define BPG  32                // blocks per group
#define RPG  8                 // batch rows per group
#define NBLK (NG*BPG)
#define NTHR 512               // 8 waves/block
#define TPG  (BPG*NTHR)

// ---- mutable state (fp64 recurrence) ----
__device__ __align__(256) double g_h0[BB*HH];
__device__ __align__(256) double g_h1[BB*HH];
__device__ __align__(256) double g_m0[BB*PP];
__device__ __align__(256) double g_m1[BB*PP];
__device__ __align__(256) double g_u0[BB*HH];
__device__ __align__(256) double g_u1[BB*HH];
__device__ __align__(256) double g_rh0[BB*HH];
__device__ __align__(256) double g_rh1[BB*HH];
__device__ __align__(256) double g_hc0[BB*HH];
__device__ __align__(256) double g_hc1[BB*HH];
__device__ __align__(256) double g_mo0[BB*PP];
__device__ __align__(256) double g_mo1[BB*PP];
__device__ __align__(256) double g_hist[(long)BB*TT*HH];
__device__ unsigned g_sync[NG*64];          // per-group cnt/gen, 256B apart

// ---- transposed weights (built once per launch by prep_weights) ----
__device__ __align__(256) float g_WrT [2*1024*512];   // [l][k][c]
__device__ __align__(256) float g_WuT [2*1024*512];
__device__ __align__(256) float g_WnT [2*1024*512];
__device__ __align__(256) float g_WmrT[2*512*256];    // [l][k][c]
__device__ __align__(256) float g_WMG [2*512*256*4];  // [l][k][pc][{mw,mu,d,s}]
__device__ __align__(256) float g_WmhT[2*256*512];    // [l][k][c]
__device__ __align__(256) float g_WoutT[512*512];     // [k][c]

struct KP {
  const float *x,*Wr,*br,*Wu,*bu,*Wn,*bn,*Wmr,*bmr,*Wmw,*bmw,*Wmu,*bmu,
              *Wmh,*bmh,*Wd,*bd,*Ws,*bs,*Wout,*bout,*dop,*ser;
  float* out;
};

__device__ inline double sigd(double x){ return 1.0/(1.0+exp(-x)); }

// 2 cols/lane: A broadcast from LDS, W coalesced from global (stride C per k)
template<int KL>
__device__ inline void dot2T(const double* a, const float* w, const int C,
                             double& o0, double& o1){
  double s0=0,s1=0,s2=0,s3=0,s4=0,s5=0,s6=0,s7=0;
  #pragma unroll 2
  for (int k=0;k<KL;k+=4){
    double2 a0 = *(const double2*)(a+k);
    double2 a1 = *(const double2*)(a+k+2);
    float2 w0 = *(const float2*)(w + (long)(k  )*C);
    float2 w1 = *(const float2*)(w + (long)(k+1)*C);
    float2 w2 = *(const float2*)(w + (long)(k+2)*C);
    float2 w3 = *(const float2*)(w + (long)(k+3)*C);
    s0 = fma(a0.x,(double)w0.x,s0); s1 = fma(a0.x,(double)w0.y,s1);
    s2 = fma(a0.y,(double)w1.x,s2); s3 = fma(a0.y,(double)w1.y,s3);
    s4 = fma(a1.x,(double)w2.x,s4); s5 = fma(a1.x,(double)w2.y,s5);
    s6 = fma(a1.y,(double)w3.x,s6); s7 = fma(a1.y,(double)w3.y,s7);
  }
  o0=(s0+s2)+(s4+s6); o1=(s1+s3)+(s5+s7);
}

// 1 col/lane
template<int KL>
__device__ inline double dot1T(const double* a, const float* w, const int C){
  double s0=0,s1=0,s2=0,s3=0;
  #pragma unroll 2
  for (int k=0;k<KL;k+=4){
    double2 a0 = *(const double2*)(a+k);
    double2 a1 = *(const double2*)(a+k+2);
    float w0 = w[(long)(k)*C], w1 = w[(long)(k+1)*C];
    float w2 = w[(long)(k+2)*C], w3 = w[(long)(k+3)*C];
    s0=fma(a0.x,(double)w0,s0); s1=fma(a0.y,(double)w1,s1);
    s2=fma(a1.x,(double)w2,s2); s3=fma(a1.y,(double)w3,s3);
  }
  return (s0+s1)+(s2+s3);
}

// write-gate quad: 4 interleaved matrices at one pcol (float4/lane), stride 1024 floats/k
template<int KL>
__device__ inline void dotMG(const double* a, const float* w4,
                             double& o0,double& o1,double& o2,double& o3){
  double s0=0,s1=0,s2=0,s3=0,t0=0,t1=0,t2=0,t3=0;
  #pragma unroll 2
  for (int k=0;k<KL;k+=2){
    double2 av = *(const double2*)(a+k);
    float4 v0 = *(const float4*)(w4 + (long)(k  )*1024);
    float4 v1 = *(const float4*)(w4 + (long)(k+1)*1024);
    s0=fma(av.x,(double)v0.x,s0); s1=fma(av.x,(double)v0.y,s1);
    s2=fma(av.x,(double)v0.z,s2); s3=fma(av.x,(double)v0.w,s3);
    t0=fma(av.y,(double)v1.x,t0); t1=fma(av.y,(double)v1.y,t1);
    t2=fma(av.y,(double)v1.z,t2); t3=fma(av.y,(double)v1.w,t3);
  }
  o0=s0+t0; o1=s1+t1; o2=s2+t2; o3=s3+t3;
}

// group-local barrier: 32 blocks, same XCD (proven pattern from prior rounds)
__device__ inline void gbar(int g){
  __syncthreads();
  if (threadIdx.x == 0){
    __threadfence();
    unsigned* cnt = &g_sync[g*64];
    unsigned* gen = &g_sync[g*64+16];
    unsigned ge  = __hip_atomic_load(gen, __ATOMIC_RELAXED, __HIP_MEMORY_SCOPE_AGENT);
    unsigned old = __hip_atomic_fetch_add(cnt, 1u, __ATOMIC_ACQ_REL, __HIP_MEMORY_SCOPE_AGENT);
    if (old == BPG-1){
      __hip_atomic_store(cnt, 0u, __ATOMIC_RELAXED, __HIP_MEMORY_SCOPE_AGENT);
      __hip_atomic_fetch_add(gen, 1u, __ATOMIC_RELEASE, __HIP_MEMORY_SCOPE_AGENT);
    } else {
      while (__hip_atomic_load(gen, __ATOMIC_ACQUIRE, __HIP_MEMORY_SCOPE_AGENT) == ge)
        __builtin_amdgcn_s_sleep(1);
    }
    __threadfence();
  }
  __syncthreads();
}

// build transposed weight layouts (one-time per launch; coalesced writes)
__global__ void __launch_bounds__(256) prep_weights(KP p)
{
  const long g0 = (long)blockIdx.x*blockDim.x + threadIdx.x;
  const long gs = (long)gridDim.x*blockDim.x;
  for (long i=g0; i<2L*1024*512; i+=gs){
    int c = (int)(i & 511), k = (int)((i>>9) & 1023), l = (int)(i>>19);
    long src = ((long)l<<19) + (long)c*1024 + k;
    g_WrT[i] = p.Wr[src]; g_WuT[i] = p.Wu[src]; g_WnT[i] = p.Wn[src];
  }
  for (long i=g0; i<2L*512*256; i+=gs){
    int c = (int)(i & 255), k = (int)((i>>8) & 511), l = (int)(i>>17);
    long src = ((long)l<<17) + (long)c*512 + k;
    g_WmrT[i] = p.Wmr[src];
    float4 v; v.x = p.Wmw[src]; v.y = p.Wmu[src]; v.z = p.Wd[src]; v.w = p.Ws[src];
    *(float4*)&g_WMG[i*4] = v;
  }
  for (long i=g0; i<2L*256*512; i+=gs){
    int c = (int)(i & 511), k = (int)((i>>9) & 255), l = (int)(i>>17);
    g_WmhT[i] = p.Wmh[((long)l<<17) + (long)c*256 + k];
  }
  for (long i=g0; i<512L*512; i+=gs){
    int c = (int)(i & 511), k = (int)(i>>9);
    g_WoutT[i] = p.Wout[(long)c*512 + k];
  }
}

__global__ void __launch_bounds__(NTHR) rnn_kernel(KP p)
{
  const int tid  = threadIdx.x;
  const int g    = blockIdx.x & (NG-1);
  const int bg   = blockIdx.x >> 3;            // 0..31 within group
  const int gtid = bg*NTHR + tid;
  const int r0   = g*RPG;
  const int iw   = tid >> 6;                   // wave in block 0..7
  const int lane = tid & 63;
  const int x    = iw*32 + bg;                 // group-wide wave-task id 0..255
  const int kq   = lane >> 4;                  // k-quarter 0..3
  const int c16  = lane & 15;

  __shared__ double sX[RPG][514];
  __shared__ double sA[RPG][514];
  __shared__ double sB[RPG][514];
  __shared__ double sC[RPG][514];
  __shared__ double sM[RPG][258];

  double* h0g = g_h0 + r0*HH;  double* h1g = g_h1 + r0*HH;
  double* m0g = g_m0 + r0*PP;  double* m1g = g_m1 + r0*PP;
  double* u0g = g_u0 + r0*HH;  double* u1g = g_u1 + r0*HH;
  double* rh0g= g_rh0+ r0*HH;  double* rh1g= g_rh1+ r0*HH;
  double* hc0g= g_hc0+ r0*HH;  double* hc1g= g_hc1+ r0*HH;
  double* mo0g= g_mo0+ r0*PP;  double* mo1g= g_mo1+ r0*PP;

  for (int i = gtid; i < RPG*HH; i += TPG){ h0g[i]=0.0; h1g[i]=0.0; }
  for (int i = gtid; i < RPG*PP; i += TPG){ m0g[i]=0.0; m1g[i]=0.0; }
  gbar(g);

  const float *WrT0 = g_WrT,  *WrT1 = g_WrT  + (1<<19);
  const float *WuT0 = g_WuT,  *WuT1 = g_WuT  + (1<<19);
  const float *WnT0 = g_WnT,  *WnT1 = g_WnT  + (1<<19);
  const float *WmrT0= g_WmrT, *WmrT1= g_WmrT + (1<<17);
  const float *WmhT0= g_WmhT, *WmhT1= g_WmhT + (1<<17);
  const float *WMG0 = g_WMG,  *WMG1 = g_WMG  + (1<<19);
  const float *br0=p.br,  *br1=p.br+HH;
  const float *bu0=p.bu,  *bu1=p.bu+HH;
  const float *bn0=p.bn,  *bn1=p.bn+HH;
  const float *bmr0=p.bmr, *bmr1=p.bmr+PP;
  const float *bmw0=p.bmw, *bmw1=p.bmw+PP;
  const float *bmu0=p.bmu, *bmu1=p.bmu+PP;
  const float *bd0=p.bd,   *bd1=p.bd+PP;
  const float *bs0=p.bs,   *bs1=p.bs+PP;
  const float *bmh0=p.bmh, *bmh1=p.bmh+HH;
  const double dopa = (double)p.dop[0];
  const double sero = (double)p.ser[0];

  auto loadD512 = [&](double dst[RPG][514], const double* src){
    for (int i = tid; i < RPG*HH/2; i += NTHR){
      int r = i >> 8, c2 = (i & 255) << 1;
      *(double2*)&dst[r][c2] = *(const double2*)(src + (i<<1));
    }
  };
  auto loadX = [&](const float* src){
    for (int i = tid; i < RPG*II/4; i += NTHR){
      int r = i >> 7, c4 = (i & 127) << 2;
      float4 v = *(const float4*)(src + (long)r*TT*II + c4);
      sX[r][c4]   = (double)v.x; sX[r][c4+1] = (double)v.y;
      sX[r][c4+2] = (double)v.z; sX[r][c4+3] = (double)v.w;
    }
  };
  auto loadM256 = [&](const double* src){
    for (int i = tid; i < RPG*PP/2; i += NTHR){
      int r = i >> 7, c2 = (i & 127) << 1;
      *(double2*)&sM[r][c2] = *(const double2*)(src + (i<<1));
    }
  };

  auto red = [&](double v){ v += __shfl_xor(v,16); v += __shfl_xor(v,32); return v; };

  // ru: 256 tasks; 2 cols/lane; K=1024 split 4 (kq<2 -> input part, else hidden part)
  auto stage_ru = [&](const double (*A1)[514], const double (*Ah)[514],
                      const float* WrT_l, const float* WuT_l,
                      const float* br_l, const float* bu_l,
                      double* rhg, double* ug){
    int row = x & 7, q = x >> 3;
    int gate = q >> 4, cb = q & 15;
    int col = cb*32 + c16*2;
    const float* w = (gate ? WuT_l : WrT_l) + kq*(256*512) + col;
    const double* a = (kq < 2) ? &A1[row][kq*256] : &Ah[row][(kq-2)*256];
    double o0,o1; dot2T<256>(a, w, 512, o0, o1);
    o0 = red(o0); o1 = red(o1);
    if (lane < 16){
      const float* bb = gate ? bu_l : br_l;
      double v0 = sigd(o0 + (double)bb[col]);
      double v1 = sigd(o1 + (double)bb[col+1]);
      long i0 = (long)row*HH + col;
      double2 st;
      if (gate){ st.x = v0; st.y = v1; *(double2*)&ug[i0] = st; }
      else     { st.x = v0*Ah[row][col]; st.y = v1*Ah[row][col+1]; *(double2*)&rhg[i0] = st; }
    }
  };
  // n: 128 tasks
  auto stage_n = [&](const double (*A1)[514], const double (*Ar)[514], const double (*Ah)[514],
                     const float* WnT_l, const float* bn_l, const double* ug, double* hcg){
    int row = x & 7, cb = x >> 3;          // 0..15
    int col = cb*32 + c16*2;
    const float* w = WnT_l + kq*(256*512) + col;
    const double* a = (kq < 2) ? &A1[row][kq*256] : &Ar[row][(kq-2)*256];
    double o0,o1; dot2T<256>(a, w, 512, o0, o1);
    o0 = red(o0); o1 = red(o1);
    if (lane < 16){
      long i0 = (long)row*HH + col;
      double n0 = tanh(o0 + (double)bn_l[col]);
      double n1 = tanh(o1 + (double)bn_l[col+1]);
      double u0v = ug[i0], u1v = ug[i0+1];
      double2 st;
      st.x = (1.0-u0v)*Ah[row][col]   + u0v*n0;
      st.y = (1.0-u1v)*Ah[row][col+1] + u1v*n1;
      *(double2*)&hcg[i0] = st;
    }
  };
  // mg quad: 128 tasks (y in [0,128))
  auto stage_mg = [&](int y, const double (*A)[514], const float* WMG_l,
                      const float* bmw_l,const float* bmu_l,const float* bd_l,const float* bs_l,
                      double* mg){
    int row = y & 7, pb = y >> 3;          // 0..15
    int pcol = pb*16 + c16;
    const float* w4 = WMG_l + kq*(128*256*4) + pcol*4;
    const double* a = &A[row][kq*128];
    double p0,p1,p2,p3; dotMG<128>(a, w4, p0,p1,p2,p3);
    p0=red(p0); p1=red(p1); p2=red(p2); p3=red(p3);
    if (lane < 16){
      double wg = sigd(p0 + (double)bmw_l[pcol]);
      double nm = tanh(p1 + (double)bmu_l[pcol]);
      double dp = sigd((p2 + (double)bd_l[pcol])*dopa);
      double sr = sigd((p3 + (double)bs_l[pcol])*sero);
      double ww = wg*dp*(1.0 - sr);
      long mi = (long)row*PP + pcol;
      mg[mi] = (1.0-ww)*mg[mi] + ww*nm;
    }
  };
  // rg: 128 tasks; 1 col/lane
  auto stage_rg = [&](const double (*Ahc)[514], const float* WmrT_l, const float* bmr_l,
                      const double* mgl, double* mog){
    int row = x & 7, cb = x >> 3;          // 0..15
    int col = cb*16 + c16;
    const float* w = WmrT_l + kq*(128*256) + col;
    double o = dot1T<128>(&Ahc[row][kq*128], w, 256);
    o = red(o);
    if (lane < 16){
      long mi = (long)row*PP + col;
      mog[mi] = sigd(o + (double)bmr_l[col]) * mgl[mi];
    }
  };
  // hm: 256 tasks; 1 col/lane; K=256 split 4
  auto stage_hm = [&](const float* WmhT_l, const float* bmh_l, const double (*Ahc)[514],
                      double* hg, bool wr_hist, int t){
    int row = x & 7, cb = x >> 3;          // 0..31
    int col = cb*16 + c16;
    const float* w = WmhT_l + kq*(64*512) + col;
    double o = dot1T<64>(&sM[row][kq*64], w, 512);
    o = red(o);
    if (lane < 16){
      long idx = (long)row*HH + col;
      double hm = o + (double)bmh_l[col] + Ahc[row][col];
      hg[idx] = hm;
      if (wr_hist) g_hist[((long)(r0+row)*TT + t)*HH + col] = hm;
    }
  };

  for (int t=0; t<TT; ++t){
    // S1: r0,u0 from [x_t, h0]; stage h1(t-1) for S2-mg1/S5/S6
    loadX(p.x + (long)r0*TT*II + (long)t*II);
    loadD512(sA, h0g);
    loadD512(sC, h1g);
    __syncthreads();
    stage_ru(sX, sA, WrT0, WuT0, br0, bu0, rh0g, u0g);
    gbar(g);
    // S2: n0 || deferred m1 update (t-1) using sC
    loadD512(sB, rh0g);
    __syncthreads();
    if (x < 128) stage_n(sX, sB, sA, WnT0, bn0, u0g, hc0g);
    else if (t > 0) stage_mg(x-128, sC, WMG1, bmw1,bmu1,bd1,bs1, m1g);
    gbar(g);
    // S3: read gate 0
    loadD512(sB, hc0g);
    __syncthreads();
    if (x < 128) stage_rg(sB, WmrT0, bmr0, m0g, mo0g);
    gbar(g);
    // S4: h_mem0 (sB = hc0 preserved)
    loadM256(mo0g);
    __syncthreads();
    stage_hm(WmhT0, bmh0, sB, h0g, false, t);
    gbar(g);
    // S5: r1,u1 from [hm0, h1]
    loadD512(sA, h0g);
    __syncthreads();
    stage_ru(sA, sC, WrT1, WuT1, br1, bu1, rh1g, u1g);
    gbar(g);
    // S6: n1 || m0 update using sA = hm0(t)
    loadD512(sB, rh1g);
    __syncthreads();
    if (x < 128) stage_n(sA, sB, sC, WnT1, bn1, u1g, hc1g);
    else stage_mg(x-128, sA, WMG0, bmw0,bmu0,bd0,bs0, m0g);
    gbar(g);
    // S7: read gate 1 (m1 already updated at S2)
    loadD512(sB, hc1g);
    __syncthreads();
    if (x < 128) stage_rg(sB, WmrT1, bmr1, m1g, mo1g);
    gbar(g);
    // S8: h_mem1 + history
    loadM256(mo1g);
    __syncthreads();
    stage_hm(WmhT1, bmh1, sB, h1g, true, t);
    gbar(g);
  }

  // flush deferred m1 update for t = TT-1
  loadD512(sC, h1g);
  __syncthreads();
  if (x < 128) stage_mg(x, sC, WMG1, bmw1,bmu1,bd1,bs1, m1g);
  gbar(g);

  // finals appended after outputs, FP32
  const long obase = (long)BB*TT*OO;
  for (int i = gtid; i < RPG*HH; i += TPG){
    int row = i >> 9, col = i & 511;
    long o = (long)(r0+row)*HH + col;
    p.out[obase + o] = (float)h0g[i];
    p.out[obase + (long)BB*HH + o] = (float)h1g[i];
  }
  for (int i = gtid; i < RPG*PP; i += TPG){
    int row = i >> 8, col = i & 255;
    long o = (long)(r0+row)*PP + col;
    p.out[obase + 2L*BB*HH + o] = (float)m0g[i];
    p.out[obase + 2L*BB*HH + (long)BB*PP + o] = (float)m1g[i];
  }
}

// outputs[b,t,:] = Wout @ h_mem1[b,t,:] + bout — LDS-staged hist rows, transposed Wout
__global__ void __launch_bounds__(512) out_gemm(const float* bout, float* out)
{
  __shared__ double sH[8][512];
  const int tid = threadIdx.x;
  const int iw = tid >> 6, lane = tid & 63;
  const int kq = lane >> 5, c32 = lane & 31;
  const int col = iw*64 + c32*2;
  const float* w = g_WoutT + kq*(256*512) + col;
  for (int rb = blockIdx.x; rb < BB*TT/8; rb += gridDim.x){
    __syncthreads();
    for (int i = tid; i < 8*256; i += 512){
      int rr = i >> 8, c2 = (i & 255) << 1;
      *(double2*)&sH[rr][c2] = *(const double2*)(g_hist + (long)(rb*8+rr)*HH + c2);
    }
    __syncthreads();
    double s[8][2];
    #pragma unroll
    for (int r=0;r<8;++r){ s[r][0]=0.0; s[r][1]=0.0; }
    #pragma unroll 2
    for (int k=0;k<256;++k){
      float2 wv = *(const float2*)(w + (long)k*512);
      double wx = (double)wv.x, wy = (double)wv.y;
      #pragma unroll
      for (int r=0;r<8;++r){
        double av = sH[r][kq*256 + k];
        s[r][0] = fma(av, wx, s[r][0]);
        s[r][1] = fma(av, wy, s[r][1]);
      }
    }
    #pragma unroll
    for (int r=0;r<8;++r){
      double t0 = s[r][0] + __shfl_xor(s[r][0],32);
      double t1 = s[r][1] + __shfl_xor(s[r][1],32);
      if (lane < 32){
        float2 fv;
        fv.x = (float)(t0 + (double)bout[col]);
        fv.y = (float)(t1 + (double)bout[col+1]);
        *(float2*)&out[(long)(rb*8+r)*OO + col] = fv;
      }
    }
  }
}

extern "C" void kernel_launch(void* const* d_in, const int* in_sizes, int n_in,
                              void* d_out, int out_size, void* d_ws, size_t ws_size,
                              hipStream_t stream)
{
  KP p;
  p.x   = (const float*)d_in[0];
  p.Wr  = (const float*)d_in[1];  p.br  = (const float*)d_in[2];
  p.Wu  = (const float*)d_in[3];  p.bu  = (const float*)d_in[4];
  p.Wn  = (const float*)d_in[5];  p.bn  = (const float*)d_in[6];
  p.Wmr = (const float*)d_in[7];  p.bmr = (const float*)d_in[8];
  p.Wmw = (const float*)d_in[9];  p.bmw = (const float*)d_in[10];
  p.Wmu = (const float*)d_in[11]; p.bmu = (const float*)d_in[12];
  p.Wmh = (const float*)d_in[13]; p.bmh = (const float*)d_in[14];
  p.Wd  = (const float*)d_in[15]; p.bd  = (const float*)d_in[16];
  p.Ws  = (const float*)d_in[17]; p.bs  = (const float*)d_in[18];
  p.Wout= (const float*)d_in[19]; p.bout= (const float*)d_in[20];
  p.dop = (const float*)d_in[21]; p.ser = (const float*)d_in[22];
  p.out = (float*)d_out;

  prep_weights<<<dim3(1024), dim3(256), 0, stream>>>(p);
  rnn_kernel<<<dim3(NBLK), dim3(NTHR), 0, stream>>>(p);
  out_gemm<<<dim3(2048), dim3(512), 0, stream>>>(p.bout, p.out);
}

// Round 3
// 98049.780 us; speedup vs baseline: 4.6069x; 1.4119x over previous
//
#include <hip/hip_runtime.h>
#include <math.h>

#define LL 2
#define BB 64
#define TT 512
#define II 512
#define HH 512
#define PP 256
#define OO 512
#define IH 1024

#define NBLK 256
#define NTHR 512
#define AGT __HIP_MEMORY_SCOPE_AGENT

// ---- mutable fp64 state; ALL cross-block accesses via agent-scope (sc1) atomics ----
__device__ __align__(256) double g_h0[BB*HH];
__device__ __align__(256) double g_h1[BB*HH];
__device__ __align__(256) double g_rh[BB*HH];    // aliased L0/L1 (phases serialized)
__device__ __align__(256) double g_hc[BB*HH];    // aliased L0/L1
__device__ __align__(256) double g_mo[BB*PP];    // aliased L0/L1
__device__ __align__(256) double g_hist[(long)BB*TT*HH];
__device__ unsigned g_grp[8*64];                 // leaf barriers (per XCD)
__device__ unsigned g_root[64];                  // root barrier

// ---- transposed weights (built once by prep_weights; L2-resident per-XCD slices) ----
__device__ __align__(256) float g_WrT [2*1024*512];   // [l][k][c]
__device__ __align__(256) float g_WuT [2*1024*512];
__device__ __align__(256) float g_WnT [2*1024*512];
__device__ __align__(256) float g_WmrT[2*512*256];    // [l][k][pc]
__device__ __align__(256) float g_WMG [2*512*256*4];  // [l][k][pc][{mw,mu,d,s}]
__device__ __align__(256) float g_WmhT[2*256*512];    // [l][k][c]
__device__ __align__(256) float g_WoutT[512*512];     // [k][c]

struct KP {
  const float *x,*Wr,*br,*Wu,*bu,*Wn,*bn,*Wmr,*bmr,*Wmw,*bmw,*Wmu,*bmu,
              *Wmh,*bmh,*Wd,*bd,*Ws,*bs,*Wout,*bout,*dop,*ser;
  float* out;
};

__device__ inline double sigd(double x){ return 1.0/(1.0+exp(-x)); }

// ---- dot kernels: A broadcast from skewed LDS, W coalesced from global (L2-hit) ----
// big buffers: 64-double chunks at stride 70
template<int NCH>
__device__ inline void dot2S(const double* a, const float* w, double& o0, double& o1){
  double s0=0,s1=0,s2=0,s3=0;
  for (int cb=0; cb<NCH; ++cb){
    const double* ab = a + cb*70;
    const float*  wb = w + (long)cb*64*512;
    #pragma unroll 16
    for (int k=0;k<64;k+=2){
      double2 av = *(const double2*)(ab+k);
      float2 w0 = *(const float2*)(wb + (long)k*512);
      float2 w1 = *(const float2*)(wb + (long)(k+1)*512);
      s0 = fma(av.x,(double)w0.x,s0); s1 = fma(av.x,(double)w0.y,s1);
      s2 = fma(av.y,(double)w1.x,s2); s3 = fma(av.y,(double)w1.y,s3);
    }
  }
  o0=s0+s2; o1=s1+s3;
}
// single 64-chunk, scalar W stride 256 (read gate)
__device__ inline double dot1S64(const double* a, const float* w){
  double s0=0,s1=0;
  #pragma unroll 16
  for (int k=0;k<64;k+=2){
    double2 av = *(const double2*)(a+k);
    s0 = fma(av.x,(double)w[(long)k*256],s0);
    s1 = fma(av.y,(double)w[(long)(k+1)*256],s1);
  }
  return s0+s1;
}
// write-gate quad: one 64-chunk, float4 interleaved W stride 1024
__device__ inline void dotMG64(const double* a, const float* w4,
                               double& o0,double& o1,double& o2,double& o3){
  double s0=0,s1=0,s2=0,s3=0,t0=0,t1=0,t2=0,t3=0;
  #pragma unroll 8
  for (int k=0;k<64;k+=2){
    double2 av = *(const double2*)(a+k);
    float4 v0 = *(const float4*)(w4 + (long)k*1024);
    float4 v1 = *(const float4*)(w4 + (long)(k+1)*1024);
    s0=fma(av.x,(double)v0.x,s0); s1=fma(av.x,(double)v0.y,s1);
    s2=fma(av.x,(double)v0.z,s2); s3=fma(av.x,(double)v0.w,s3);
    t0=fma(av.y,(double)v1.x,t0); t1=fma(av.y,(double)v1.y,t1);
    t2=fma(av.y,(double)v1.z,t2); t3=fma(av.y,(double)v1.w,t3);
  }
  o0=s0+t0;o1=s1+t1;o2=s2+t2;o3=s3+t3;
}
// 32-double chunk (sM), W stride 512
__device__ inline void dot2S32(const double* a, const float* w, double& o0,double& o1){
  double s0=0,s1=0,s2=0,s3=0;
  #pragma unroll 8
  for (int k=0;k<32;k+=2){
    double2 av=*(const double2*)(a+k);
    float2 w0=*(const float2*)(w+(long)k*512), w1=*(const float2*)(w+(long)(k+1)*512);
    s0=fma(av.x,(double)w0.x,s0); s1=fma(av.x,(double)w0.y,s1);
    s2=fma(av.y,(double)w1.x,s2); s3=fma(av.y,(double)w1.y,s3);
  }
  o0=s0+s2;o1=s1+s3;
}
// fp64-accum dot, A fp64 in global (out_gemm)
__device__ inline double dotD(const double* a, const float* w, int K){
  double s0=0,s1=0,s2=0,s3=0;
  #pragma unroll 4
  for (int k=0;k<K;k+=4){
    double2 a0 = *(const double2*)(a+k);
    double2 a1 = *(const double2*)(a+k+2);
    float4 wv = *(const float4*)(w+k);
    s0 = fma(a0.x,(double)wv.x,s0);
    s1 = fma(a0.y,(double)wv.y,s1);
    s2 = fma(a1.x,(double)wv.z,s2);
    s3 = fma(a1.y,(double)wv.w,s3);
  }
  return (s0+s1)+(s2+s3);
}

// ---- device-wide hierarchical barrier: NO acquire fences, NO buffer_inv.
// State crosses via sc1 (agent) loads/stores served at L3; RELEASE adds emit
// waitcnt+wbl2 only, so clean (weight) L2 lines survive every barrier.
__device__ inline void gbar(int g){
  __syncthreads();
  if (threadIdx.x==0){
    unsigned* gcnt=&g_grp[g*64]; unsigned* ggen=&g_grp[g*64+16];
    unsigned gg=__hip_atomic_load(ggen,__ATOMIC_RELAXED,AGT);
    unsigned old=__hip_atomic_fetch_add(gcnt,1u,__ATOMIC_RELEASE,AGT);
    if (old==31u){
      __hip_atomic_store(gcnt,0u,__ATOMIC_RELAXED,AGT);
      unsigned* rcnt=&g_root[0]; unsigned* rgen=&g_root[16];
      unsigned rg=__hip_atomic_load(rgen,__ATOMIC_RELAXED,AGT);
      unsigned ro=__hip_atomic_fetch_add(rcnt,1u,__ATOMIC_RELEASE,AGT);
      if (ro==7u){
        __hip_atomic_store(rcnt,0u,__ATOMIC_RELAXED,AGT);
        __hip_atomic_fetch_add(rgen,1u,__ATOMIC_RELEASE,AGT);
      } else {
        while(__hip_atomic_load(rgen,__ATOMIC_RELAXED,AGT)==rg) __builtin_amdgcn_s_sleep(1);
      }
      __hip_atomic_fetch_add(ggen,1u,__ATOMIC_RELEASE,AGT);
    } else {
      while(__hip_atomic_load(ggen,__ATOMIC_RELAXED,AGT)==gg) __builtin_amdgcn_s_sleep(1);
    }
    asm volatile("" ::: "memory");
  }
  __syncthreads();
}

// build transposed weight layouts (one-time; coalesced writes)
__global__ void __launch_bounds__(256) prep_weights(KP p)
{
  const long g0 = (long)blockIdx.x*blockDim.x + threadIdx.x;
  const long gs = (long)gridDim.x*blockDim.x;
  for (long i=g0; i<2L*1024*512; i+=gs){
    int c = (int)(i & 511), k = (int)((i>>9) & 1023), l = (int)(i>>19);
    long src = ((long)l<<19) + (long)c*1024 + k;
    g_WrT[i] = p.Wr[src]; g_WuT[i] = p.Wu[src]; g_WnT[i] = p.Wn[src];
  }
  for (long i=g0; i<2L*512*256; i+=gs){
    int c = (int)(i & 255), k = (int)((i>>8) & 511), l = (int)(i>>17);
    long src = ((long)l<<17) + (long)c*512 + k;
    g_WmrT[i] = p.Wmr[src];
    float4 v; v.x = p.Wmw[src]; v.y = p.Wmu[src]; v.z = p.Wd[src]; v.w = p.Ws[src];
    *(float4*)&g_WMG[i*4] = v;
  }
  for (long i=g0; i<2L*256*512; i+=gs){
    int c = (int)(i & 511), k = (int)((i>>9) & 255), l = (int)(i>>17);
    g_WmhT[i] = p.Wmh[((long)l<<17) + (long)c*256 + k];
  }
  for (long i=g0; i<512L*512; i+=gs){
    int c = (int)(i & 511), k = (int)(i>>9);
    g_WoutT[i] = p.Wout[(long)c*512 + k];
  }
}

__global__ void __launch_bounds__(NTHR) rnn_kernel(KP p)
{
  const int tid  = threadIdx.x;
  const int xcd  = blockIdx.x & 7;          // col-slice owner (L2-resident weights)
  const int cs   = (blockIdx.x >> 3) & 3;   // col sub-slice
  const int rb   = blockIdx.x >> 5;         // row block (8 rows)
  const int iw   = tid >> 6;                // wave = row 0..7
  const int lane = tid & 63;
  const int r0g  = rb*8;
  const int colH0 = xcd*64 + cs*16;
  const int colP0 = xcd*32 + cs*8;

  // skewed LDS: 64-dbl chunks at stride 70 (K-split broadcast <=2-way bank alias)
  __shared__ double sX[8][560];
  __shared__ double sA[8][560];   // h0-era / h_mem0
  __shared__ double sB[8][560];   // rh / hc
  __shared__ double sC[8][560];   // h1(t-1)
  __shared__ double sM[8][272];   // mem_out (32-dbl chunks at stride 34)
  __shared__ double su[8][16];    // update gate (own cols, block-local)
  __shared__ double sm0[8][8], sm1[8][8];   // memory state (own pcols, block-local)

  auto fH = [](int k){ return (k>>6)*70 + (k&63); };

  // prologue: zero local state (no global init, no initial device barrier needed)
  for (int i=tid;i<8*560;i+=NTHR){ int r=i/560, c=i%560; sA[r][c]=0.0; sC[r][c]=0.0; }
  if (tid<64){ sm0[tid>>3][tid&7]=0.0; sm1[tid>>3][tid&7]=0.0; }
  __syncthreads();

  const float *WrT0 = g_WrT,  *WrT1 = g_WrT  + (1<<19);
  const float *WuT0 = g_WuT,  *WuT1 = g_WuT  + (1<<19);
  const float *WnT0 = g_WnT,  *WnT1 = g_WnT  + (1<<19);
  const float *WmrT0= g_WmrT, *WmrT1= g_WmrT + (1<<17);
  const float *WmhT0= g_WmhT, *WmhT1= g_WmhT + (1<<17);
  const float *WMG0 = g_WMG,  *WMG1 = g_WMG  + (1<<19);
  const float *br0=p.br,  *br1=p.br+HH;
  const float *bu0=p.bu,  *bu1=p.bu+HH;
  const float *bn0=p.bn,  *bn1=p.bn+HH;
  const float *bmr0=p.bmr, *bmr1=p.bmr+PP;
  const float *bmw0=p.bmw, *bmw1=p.bmw+PP;
  const float *bmu0=p.bmu, *bmu1=p.bmu+PP;
  const float *bd0=p.bd,   *bd1=p.bd+PP;
  const float *bs0=p.bs,   *bs1=p.bs+PP;
  const float *bmh0=p.bmh, *bmh1=p.bmh+HH;
  const double dopa = (double)p.dop[0];
  const double sero = (double)p.ser[0];

  auto ald = [](const double* pd){ return __hip_atomic_load(pd, __ATOMIC_RELAXED, AGT); };
  auto ast = [](double* pd, double v){ __hip_atomic_store(pd, v, __ATOMIC_RELAXED, AGT); };

  // ---- sc1 staging: ILP-batched loads, then LDS writes ----
  auto ldst512 = [&](double dst[8][560], const double* src){  // src = g_xxx + r0g*512
    double v[8];
    #pragma unroll
    for (int j=0;j<8;++j) v[j] = __hip_atomic_load(src + j*512 + tid, __ATOMIC_RELAXED, AGT);
    int idx = tid + ((tid>>6)<<1) + ((tid>>6)<<2);  // (tid>>6)*70 + (tid&63) == tid + 6*(tid>>6)
    #pragma unroll
    for (int j=0;j<8;++j) dst[j][idx] = v[j];
  };
  auto ldst256 = [&](const double* src){
    double v[4];
    #pragma unroll
    for (int j=0;j<4;++j) v[j] = __hip_atomic_load(src + j*512 + tid, __ATOMIC_RELAXED, AGT);
    #pragma unroll
    for (int j=0;j<4;++j){
      int idx = j*512 + tid; int r = idx>>8, k = idx&255;
      sM[r][(k>>5)*34 + (k&31)] = v[j];
    }
  };
  auto loadX = [&](int t){  // plain cacheable (immutable input)
    float2 v[4];
    #pragma unroll
    for (int j=0;j<4;++j){
      int idx = j*512 + tid; int r = idx>>8, c2 = (idx&255)<<1;
      v[j] = *(const float2*)(p.x + ((long)(r0g+r)*TT + t)*II + c2);
    }
    #pragma unroll
    for (int j=0;j<4;++j){
      int idx = j*512 + tid; int r = idx>>8, c2 = (idx&255)<<1;
      int s = fH(c2);
      sX[r][s] = (double)v[j].x; sX[r][s+1] = (double)v[j].y;
    }
  };

  auto red16 = [&](double v){ v+=__shfl_xor(v,8); v+=__shfl_xor(v,16); return v; };
  auto red32 = [&](double v){ v+=__shfl_xor(v,8); v+=__shfl_xor(v,16); v+=__shfl_xor(v,32); return v; };

  // ---- stages (wave iw = row; all 64 lanes busy) ----
  // ru: half-wave = gate; ks=(lane>>3)&3 K-quarter (0,1:A1 / 2,3:Ah); c8 col-pair
  auto stage_ru = [&](const double (*A1)[560], const double (*Ah)[560],
                      const float* WrT_l, const float* WuT_l,
                      const float* br_l, const float* bu_l){
    int row=iw, gate=lane>>5, ks=(lane>>3)&3, c8=lane&7;
    int col = colH0 + c8*2;
    const float* w = (gate?WuT_l:WrT_l) + (long)ks*256*512 + col;
    const double* a = (ks<2) ? &A1[row][280*ks] : &Ah[row][280*(ks-2)];
    double o0,o1; dot2S<4>(a, w, o0, o1);
    o0 = red16(o0); o1 = red16(o1);
    if ((lane&24)==0){
      const float* bb = gate?bu_l:br_l;
      double v0 = sigd(o0 + (double)bb[col]);
      double v1 = sigd(o1 + (double)bb[col+1]);
      if (gate){ su[row][c8*2] = v0; su[row][c8*2+1] = v1; }
      else {
        long gi = (long)(r0g+row)*HH + col;
        ast(&g_rh[gi],   v0 * Ah[row][fH(col)]);
        ast(&g_rh[gi+1], v1 * Ah[row][fH(col+1)]);
      }
    }
  };
  // n: ks=lane>>3 over 8 halves of 128 (0..3: A1, 4..7: rh=sB)
  auto stage_n = [&](const double (*A1)[560], const double (*Ah)[560],
                     const float* WnT_l, const float* bn_l){
    int row=iw, ks=lane>>3, c8=lane&7;
    int col = colH0 + c8*2;
    const float* w = WnT_l + (long)ks*128*512 + col;
    const double* a = (ks<4) ? &A1[row][140*ks] : &sB[row][140*(ks-4)];
    double o0,o1; dot2S<2>(a, w, o0, o1);
    o0 = red32(o0); o1 = red32(o1);
    if (lane<8){
      double n0 = tanh(o0 + (double)bn_l[col]);
      double n1 = tanh(o1 + (double)bn_l[col+1]);
      double u0 = su[row][c8*2], u1 = su[row][c8*2+1];
      long gi = (long)(r0g+row)*HH + col;
      ast(&g_hc[gi],   (1.0-u0)*Ah[row][fH(col)]   + u0*n0);
      ast(&g_hc[gi+1], (1.0-u1)*Ah[row][fH(col+1)] + u1*n1);
    }
  };
  // write-gate quad: updates block-local m; A = h_mem buffer
  auto stage_mg = [&](const double (*A)[560], const float* WMG_l,
                      const float* bmw_l,const float* bmu_l,const float* bd_l,const float* bs_l,
                      double (*smx)[8]){
    int row=iw, ks=lane>>3, pc=lane&7;
    int pcol = colP0 + pc;
    const float* w4 = WMG_l + (long)ks*64*1024 + pcol*4;
    const double* a = &A[row][70*ks];
    double p0,p1,p2,p3; dotMG64(a, w4, p0,p1,p2,p3);
    p0=red32(p0); p1=red32(p1); p2=red32(p2); p3=red32(p3);
    if (lane<8){
      double wg = sigd(p0 + (double)bmw_l[pcol]);
      double nm = tanh(p1 + (double)bmu_l[pcol]);
      double dp = sigd((p2 + (double)bd_l[pcol])*dopa);
      double sr = sigd((p3 + (double)bs_l[pcol])*sero);
      double ww = wg*dp*(1.0 - sr);
      smx[row][pc] = (1.0-ww)*smx[row][pc] + ww*nm;
    }
  };
  // read gate: A = hc (sB); own m from LDS; mo -> global sc1
  auto stage_rg = [&](const float* WmrT_l, const float* bmr_l, double (*smx)[8]){
    int row=iw, ks=lane>>3, pc=lane&7;
    int pcol = colP0 + pc;
    const float* w = WmrT_l + (long)ks*64*256 + pcol;
    double o = dot1S64(&sB[row][70*ks], w);
    o = red32(o);
    if (lane<8){
      ast(&g_mo[(long)(r0g+row)*PP + pcol],
          sigd(o + (double)bmr_l[pcol]) * smx[row][pc]);
    }
  };
  // h_mem: A = sM; + hc (sB); h -> global sc1 (+hist)
  auto stage_hm = [&](const float* WmhT_l, const float* bmh_l, double* hg, int t, bool wr_hist){
    int row=iw, ks=lane>>3, c8=lane&7;
    int col = colH0 + c8*2;
    const float* w = WmhT_l + (long)ks*32*512 + col;
    double o0,o1; dot2S32(&sM[row][34*ks], w, o0,o1);
    o0 = red32(o0); o1 = red32(o1);
    if (lane<8){
      double h0v = o0 + (double)bmh_l[col]   + sB[row][fH(col)];
      double h1v = o1 + (double)bmh_l[col+1] + sB[row][fH(col+1)];
      long gi = (long)(r0g+row)*HH + col;
      ast(&hg[gi], h0v); ast(&hg[gi+1], h1v);
      if (wr_hist){
        long hb = ((long)(r0g+row)*TT + t)*HH + col;
        __builtin_nontemporal_store(h0v, &g_hist[hb]);
        __builtin_nontemporal_store(h1v, &g_hist[hb+1]);
      }
    }
  };

  const double* h0src = g_h0 + (long)r0g*HH;
  const double* h1src = g_h1 + (long)r0g*HH;
  const double* rhsrc = g_rh + (long)r0g*HH;
  const double* hcsrc = g_hc + (long)r0g*HH;
  const double* mosrc = g_mo + (long)r0g*PP;

  for (int t=0; t<TT; ++t){
    // S1: ru0 from [x_t, h0]  ||  deferred mg1 (uses h1(t-1)=sC)
    loadX(t);
    if (t>0) ldst512(sC, h1src);
    __syncthreads();
    stage_ru(sX, sA, WrT0, WuT0, br0, bu0);
    if (t>0) stage_mg(sC, WMG1, bmw1,bmu1,bd1,bs1, sm1);
    gbar(xcd);
    // S2: n0 -> h_cand0
    ldst512(sB, rhsrc);
    __syncthreads();
    stage_n(sX, sA, WnT0, bn0);
    gbar(xcd);
    // S3: read gate 0 -> mem_out0
    ldst512(sB, hcsrc);
    __syncthreads();
    stage_rg(WmrT0, bmr0, sm0);
    gbar(xcd);
    // S4: h_mem0 (sB = hc0 kept)
    ldst256(mosrc);
    __syncthreads();
    stage_hm(WmhT0, bmh0, g_h0, t, false);
    gbar(xcd);
    // S5: ru1 from [h_mem0, h1]  ||  mg0 (uses h_mem0 = sA)
    ldst512(sA, h0src);
    __syncthreads();
    stage_ru(sA, sC, WrT1, WuT1, br1, bu1);
    stage_mg(sA, WMG0, bmw0,bmu0,bd0,bs0, sm0);
    gbar(xcd);
    // S6: n1 -> h_cand1
    ldst512(sB, rhsrc);
    __syncthreads();
    stage_n(sA, sC, WnT1, bn1);
    gbar(xcd);
    // S7: read gate 1
    ldst512(sB, hcsrc);
    __syncthreads();
    stage_rg(WmrT1, bmr1, sm1);
    gbar(xcd);
    // S8: h_mem1 (+ fp64 history)
    ldst256(mosrc);
    __syncthreads();
    stage_hm(WmhT1, bmh1, g_h1, t, true);
    gbar(xcd);
  }

  // flush deferred m1 update for t = TT-1
  ldst512(sC, h1src);
  __syncthreads();
  stage_mg(sC, WMG1, bmw1,bmu1,bd1,bs1, sm1);
  __syncthreads();

  // finals appended after outputs, FP32: each block writes its (rows x col-window)
  const long obase = (long)BB*TT*OO;
  for (int i = tid; i < 8*16; i += NTHR){
    int r = i >> 4, c = i & 15;
    int col = colH0 + c; long b = r0g + r;
    p.out[obase + b*HH + col]                 = (float)ald(&g_h0[b*HH+col]);
    p.out[obase + (long)BB*HH + b*HH + col]   = (float)ald(&g_h1[b*HH+col]);
  }
  for (int i = tid; i < 8*8; i += NTHR){
    int r = i >> 3, pc = i & 7;
    int pcol = colP0 + pc; long b = r0g + r;
    p.out[obase + 2L*BB*HH + b*PP + pcol]                 = (float)sm0[r][pc];
    p.out[obase + 2L*BB*HH + (long)BB*PP + b*PP + pcol]   = (float)sm1[r][pc];
  }
}

// outputs[b,t,:] = Wout @ h_mem1[b,t,:] + bout — LDS-staged hist rows, transposed Wout
__global__ void __launch_bounds__(512) out_gemm(const float* bout, float* out)
{
  __shared__ double sH[8][512];
  const int tid = threadIdx.x;
  const int iw = tid >> 6, lane = tid & 63;
  const int kq = lane >> 5, c32 = lane & 31;
  const int col = iw*64 + c32*2;
  const float* w = g_WoutT + kq*(256*512) + col;
  for (int rbx = blockIdx.x; rbx < BB*TT/8; rbx += gridDim.x){
    __syncthreads();
    for (int i = tid; i < 8*256; i += 512){
      int rr = i >> 8, c2 = (i & 255) << 1;
      *(double2*)&sH[rr][c2] = *(const double2*)(g_hist + (long)(rbx*8+rr)*HH + c2);
    }
    __syncthreads();
    double s[8][2];
    #pragma unroll
    for (int r=0;r<8;++r){ s[r][0]=0.0; s[r][1]=0.0; }
    #pragma unroll 2
    for (int k=0;k<256;++k){
      float2 wv = *(const float2*)(w + (long)k*512);
      double wx = (double)wv.x, wy = (double)wv.y;
      #pragma unroll
      for (int r=0;r<8;++r){
        double av = sH[r][kq*256 + k];
        s[r][0] = fma(av, wx, s[r][0]);
        s[r][1] = fma(av, wy, s[r][1]);
      }
    }
    #pragma unroll
    for (int r=0;r<8;++r){
      double t0 = s[r][0] + __shfl_xor(s[r][0],32);
      double t1 = s[r][1] + __shfl_xor(s[r][1],32);
      if (lane < 32){
        float2 fv;
        fv.x = (float)(t0 + (double)bout[col]);
        fv.y = (float)(t1 + (double)bout[col+1]);
        *(float2*)&out[(long)(rbx*8+r)*OO + col] = fv;
      }
    }
  }
}

extern "C" void kernel_launch(void* const* d_in, const int* in_sizes, int n_in,
                              void* d_out, int out_size, void* d_ws, size_t ws_size,
                              hipStream_t stream)
{
  KP p;
  p.x   = (const float*)d_in[0];
  p.Wr  = (const float*)d_in[1];  p.br  = (const float*)d_in[2];
  p.Wu  = (const float*)d_in[3];  p.bu  = (const float*)d_in[4];
  p.Wn  = (const float*)d_in[5];  p.bn  = (const float*)d_in[6];
  p.Wmr = (const float*)d_in[7];  p.bmr = (const float*)d_in[8];
  p.Wmw = (const float*)d_in[9];  p.bmw = (const float*)d_in[10];
  p.Wmu = (const float*)d_in[11]; p.bmu = (const float*)d_in[12];
  p.Wmh = (const float*)d_in[13]; p.bmh = (const float*)d_in[14];
  p.Wd  = (const float*)d_in[15]; p.bd  = (const float*)d_in[16];
  p.Ws  = (const float*)d_in[17]; p.bs  = (const float*)d_in[18];
  p.Wout= (const float*)d_in[19]; p.bout= (const float*)d_in[20];
  p.dop = (const float*)d_in[21]; p.ser = (const float*)d_in[22];
  p.out = (float*)d_out;

  prep_weights<<<dim3(1024), dim3(256), 0, stream>>>(p);
  rnn_kernel<<<dim3(NBLK), dim3(NTHR), 0, stream>>>(p);
  out_gemm<<<dim3(2048), dim3(512), 0, stream>>>(p.bout, p.out);
}

// Round 4
// 57566.742 us; speedup vs baseline: 7.8466x; 1.7032x over previous
//
#include <hip/hip_runtime.h>
#include <math.h>

#define BB 64
#define TT 512
#define II 512
#define HH 512
#define PP 256
#define OO 512

#define NTHR 512
#define AGT __HIP_MEMORY_SCOPE_AGENT

// ---- mutable fp64 state; all cross-block accesses via agent-scope (sc1) relaxed atomics ----
__device__ __align__(256) double g_h0d[2*BB*HH];   // double-buffered h_mem0 (by t&1)
__device__ __align__(256) double g_h1 [BB*HH];
__device__ __align__(256) double g_rh [2*BB*HH];   // per-layer
__device__ __align__(256) double g_hc [2*BB*HH];
__device__ __align__(256) double g_mo [2*BB*PP];
__device__ __align__(256) double g_hist[(long)BB*TT*HH];
__device__ unsigned g_sync[2048];                  // 16 groups x 4 stages, 128B apart

// ---- transposed weights (built by prep; per-XCD slices L2-resident) ----
__device__ __align__(256) float g_WRU [2*1024*1024];  // [l][k][c*2+{r,u}]
__device__ __align__(256) float g_WnT [2*1024*512];   // [l][k][c]
__device__ __align__(256) float g_WMG [2*512*1024];   // [l][k][pc*4+{mw,mu,d,s}]
__device__ __align__(256) float g_WmrT[2*512*256];    // [l][k][pc]
__device__ __align__(256) float g_WmhT[2*256*512];    // [l][k][c]
__device__ __align__(256) float g_WoutT[512*512];     // [k][c]

struct KP {
  const float *x,*Wr,*br,*Wu,*bu,*Wn,*bn,*Wmr,*bmr,*Wmw,*bmw,*Wmu,*bmu,
              *Wmh,*bmh,*Wd,*bd,*Ws,*bs,*Wout,*bout,*dop,*ser;
  float* out;
};

__device__ inline double sigd(double x){ return 1.0/(1.0+exp(-x)); }

// ---- prep: LDS-tiled transposes (both sides coalesced) + state/sync zeroing ----
__global__ void __launch_bounds__(256) prep(KP p)
{
  __shared__ float tile[32][33];
  const int b = blockIdx.x;
  const int T_RUN = 3072;          // Wr,Wu,Wn: 3 x (2l x 512 tiles)
  const int T_MG  = T_RUN + 1024;  // Wmw,Wmu,Wd,Ws: 4 x (2l x 128)
  const int T_MR  = T_MG  + 256;
  const int T_MH  = T_MR  + 256;
  const int T_OUT = T_MH  + 256;
  const int tid = threadIdx.x;

  const float* src = nullptr; float* dst = nullptr;
  int K=0, C=0, st=1, off=0, k0=0, c0=0;
  bool xpose = true;

  if (b < T_RUN){
    int m = b >> 10, r = b & 1023, l = r >> 9, t = r & 511;
    K=1024; C=512; int ct = t & 15, kt = t >> 4; k0=kt*32; c0=ct*32;
    src = (m==0? p.Wr : m==1? p.Wu : p.Wn) + (long)l*C*K;
    if (m<2){ dst = g_WRU + (long)l*1024*1024; st=2; off=m; }
    else    { dst = g_WnT + (long)l*1024*512;  st=1; off=0; }
  } else if (b < T_MG){
    int q = b - T_RUN, m = q >> 8, r = q & 255, l = r >> 7, t = r & 127;
    K=512; C=256; int ct = t & 7, kt = t >> 3; k0=kt*32; c0=ct*32;
    const float* s4[4] = {p.Wmw,p.Wmu,p.Wd,p.Ws};
    src = s4[m] + (long)l*C*K;
    dst = g_WMG + (long)l*512*1024; st=4; off=m;
  } else if (b < T_MR){
    int r = b - T_MG, l = r >> 7, t = r & 127;
    K=512; C=256; int ct = t & 7, kt = t >> 3; k0=kt*32; c0=ct*32;
    src = p.Wmr + (long)l*C*K;
    dst = g_WmrT + (long)l*512*256; st=1; off=0;
  } else if (b < T_MH){
    int r = b - T_MR, l = r >> 7, t = r & 127;
    K=256; C=512; int ct = t & 15, kt = t >> 4; k0=kt*32; c0=ct*32;
    src = p.Wmh + (long)l*C*K;
    dst = g_WmhT + (long)l*256*512; st=1; off=0;
  } else if (b < T_OUT){
    int t = b - T_MH;
    K=512; C=512; int ct = t & 15, kt = t >> 4; k0=kt*32; c0=ct*32;
    src = p.Wout; dst = g_WoutT; st=1; off=0;
  } else {
    xpose = false;
    long i = (long)(b - T_OUT)*256 + tid;
    if (i < 2L*BB*HH) g_h0d[i] = 0.0;
    if (i < (long)BB*HH) g_h1[i] = 0.0;
    if (i < 2048) g_sync[(int)i] = 0u;
  }

  if (xpose){
    for (int i=tid; i<1024; i+=256){
      int ty=i>>5, tx=i&31;
      tile[ty][tx] = src[(long)(c0+ty)*K + k0+tx];
    }
    __syncthreads();
    for (int i=tid; i<1024; i+=256){
      int ky=i>>5, cx=i&31;
      dst[(long)(k0+ky)*C*st + (long)(c0+cx)*st + off] = tile[cx][ky];
    }
  }
}

// ---- main: 2-layer software pipeline, 16-block row-group barriers ----
__global__ void __launch_bounds__(NTHR) rnn_kernel(KP p)
{
  const int tid  = threadIdx.x;
  const int xcd  = blockIdx.x & 7;
  const int lay  = xcd >> 2;                 // 0: layer-0 chain; 1: layer-1 chain
  const int xl   = xcd & 3;
  const int cs   = (blockIdx.x >> 3) & 3;
  const int rb   = blockIdx.x >> 5;          // row group 0..7
  const int row  = tid >> 6;                 // wave = batch row 0..7
  const int lane = tid & 63;
  const int r0g  = rb*8;
  const int colH0 = xl*128 + cs*32;          // 32 hidden cols per block
  const int colP0 = xl*64  + cs*16;          // 16 mem cols per block

  __shared__ double sP[8][512];   // x_t (L0) / h_mem0(t) (L1)
  __shared__ double sH[8][512];   // own-layer h state (h_mem(t-1))
  __shared__ double sB[8][512];   // rh / hc
  __shared__ double sM[8][256];   // mem_out
  __shared__ double su[8][32];    // update gate (own cols)
  __shared__ double sm[8][16];    // memory state (own pcols)

  if (tid < 128) sm[tid>>4][tid&15] = 0.0;

  const float* WRU = g_WRU  + (long)lay*1024*1024;
  const float* WN  = g_WnT  + (long)lay*1024*512;
  const float* WMGp= g_WMG  + (long)lay*512*1024;
  const float* WMR = g_WmrT + (long)lay*512*256;
  const float* WMH = g_WmhT + (long)lay*256*512;
  const float* br_ = p.br + lay*HH; const float* bu_ = p.bu + lay*HH;
  const float* bn_ = p.bn + lay*HH; const float* bmh_= p.bmh+ lay*HH;
  const float* bmr_= p.bmr+ lay*PP; const float* bmw_= p.bmw+ lay*PP;
  const float* bmu_= p.bmu+ lay*PP; const float* bd_ = p.bd + lay*PP;
  const float* bs_ = p.bs + lay*PP;
  const double dopa = (double)p.dop[0];
  const double sero = (double)p.ser[0];

  double* rhG = g_rh + (long)lay*BB*HH + (long)r0g*HH;
  double* hcG = g_hc + (long)lay*BB*HH + (long)r0g*HH;
  double* moG = g_mo + (long)lay*BB*PP + (long)r0g*PP;

  auto bidx = [&](int l, int s){ return (((rb<<1)|l)<<2 | s)<<5; };

  auto bar = [&](int s){
    __syncthreads();
    if (tid==0){
      unsigned* cnt = &g_sync[bidx(lay,s)];
      unsigned* gen = cnt + 16;
      unsigned ge  = __hip_atomic_load(gen,__ATOMIC_RELAXED,AGT);
      unsigned old = __hip_atomic_fetch_add(cnt,1u,__ATOMIC_RELEASE,AGT);
      if (old==15u){
        __hip_atomic_store(cnt,0u,__ATOMIC_RELAXED,AGT);
        __hip_atomic_fetch_add(gen,1u,__ATOMIC_RELEASE,AGT);
      } else {
        while(__hip_atomic_load(gen,__ATOMIC_RELAXED,AGT)==ge) __builtin_amdgcn_s_sleep(1);
      }
      asm volatile("" ::: "memory");
    }
    __syncthreads();
  };
  auto wait_ge = [&](int l, int s, unsigned v){
    if (tid==0){
      unsigned* gen = &g_sync[bidx(l,s)] + 16;
      while(__hip_atomic_load(gen,__ATOMIC_RELAXED,AGT) < v) __builtin_amdgcn_s_sleep(1);
      asm volatile("" ::: "memory");
    }
    __syncthreads();
  };

  // sc1 staging (rows contiguous; consecutive lanes -> consecutive doubles)
  auto ld512 = [&](double dst[8][512], const double* src){
    double v[8];
    #pragma unroll
    for (int j=0;j<8;++j) v[j] = __hip_atomic_load(src + (long)j*HH + tid, __ATOMIC_RELAXED, AGT);
    #pragma unroll
    for (int j=0;j<8;++j) dst[j][tid] = v[j];
  };
  auto ld256 = [&](const double* src){
    double v[4];
    #pragma unroll
    for (int j=0;j<4;++j){
      int idx = j*512 + tid;
      v[j] = __hip_atomic_load(src + (long)(idx>>8)*PP + (idx&255), __ATOMIC_RELAXED, AGT);
    }
    #pragma unroll
    for (int j=0;j<4;++j){
      int idx = j*512 + tid;
      sM[idx>>8][idx&255] = v[j];
    }
  };
  auto ldX = [&](int t){
    float v[8];
    #pragma unroll
    for (int j=0;j<8;++j) v[j] = p.x[((long)(r0g+j)*TT + t)*II + tid];
    #pragma unroll
    for (int j=0;j<8;++j) sP[j][tid] = (double)v[j];
  };

  // ---- stages (wave = row; A broadcast from LDS; W coalesced, L2-resident) ----
  auto ruS = [&](){
    const int c = lane&31, ks = lane>>5;
    const int col = colH0 + c;
    const float* w = WRU + (long)(ks*512)*1024 + col*2;
    const double* a = ks ? &sH[row][0] : &sP[row][0];
    double r0=0,r1=0,u0=0,u1=0;
    #pragma unroll 8
    for (int k=0;k<512;k+=2){
      double2 av = *(const double2*)(a+k);
      float2 w0 = *(const float2*)(w + (long)k*1024);
      float2 w1 = *(const float2*)(w + (long)(k+1)*1024);
      r0 = fma(av.x,(double)w0.x,r0); u0 = fma(av.x,(double)w0.y,u0);
      r1 = fma(av.y,(double)w1.x,r1); u1 = fma(av.y,(double)w1.y,u1);
    }
    double orr=r0+r1, ouu=u0+u1;
    orr += __shfl_xor(orr,32); ouu += __shfl_xor(ouu,32);
    if (lane<32){
      double r = sigd(orr + (double)br_[col]);
      double u = sigd(ouu + (double)bu_[col]);
      su[row][c] = u;
      __hip_atomic_store(&rhG[(long)row*HH+col], r*sH[row][col], __ATOMIC_RELAXED, AGT);
    }
  };
  auto mgS = [&](){
    const int pc = lane&15, ks = lane>>4;
    const int pcol = colP0 + pc;
    const float* w4 = WMGp + (long)(ks*128)*1024 + pcol*4;
    const double* a = &sH[row][ks*128];
    double q0=0,q1=0,q2=0,q3=0;
    #pragma unroll 8
    for (int k=0;k<128;++k){
      int kk = (k + (ks<<2)) & 127;            // bank de-phase across ks groups
      double av = a[kk];
      float4 v = *(const float4*)(w4 + (long)kk*1024);
      q0=fma(av,(double)v.x,q0); q1=fma(av,(double)v.y,q1);
      q2=fma(av,(double)v.z,q2); q3=fma(av,(double)v.w,q3);
    }
    q0+=__shfl_xor(q0,16); q0+=__shfl_xor(q0,32);
    q1+=__shfl_xor(q1,16); q1+=__shfl_xor(q1,32);
    q2+=__shfl_xor(q2,16); q2+=__shfl_xor(q2,32);
    q3+=__shfl_xor(q3,16); q3+=__shfl_xor(q3,32);
    if (lane<16){
      double wg = sigd(q0 + (double)bmw_[pcol]);
      double nm = tanh(q1 + (double)bmu_[pcol]);
      double dp = sigd((q2 + (double)bd_[pcol])*dopa);
      double sr = sigd((q3 + (double)bs_[pcol])*sero);
      double ww = wg*dp*(1.0 - sr);
      sm[row][pc] = (1.0-ww)*sm[row][pc] + ww*nm;
    }
  };
  auto nS = [&](){
    const int c = lane&31, ks = lane>>5;
    const int col = colH0 + c;
    const float* w = WN + (long)(ks*512)*512 + col;
    const double* a = ks ? &sB[row][0] : &sP[row][0];
    double a0=0,a1=0,a2=0,a3=0;
    #pragma unroll 4
    for (int k=0;k<512;k+=4){
      double2 v0 = *(const double2*)(a+k), v1 = *(const double2*)(a+k+2);
      a0 = fma(v0.x,(double)w[(long)k*512],    a0);
      a1 = fma(v0.y,(double)w[(long)(k+1)*512],a1);
      a2 = fma(v1.x,(double)w[(long)(k+2)*512],a2);
      a3 = fma(v1.y,(double)w[(long)(k+3)*512],a3);
    }
    double o = (a0+a1)+(a2+a3);
    o += __shfl_xor(o,32);
    if (lane<32){
      double nh = tanh(o + (double)bn_[col]);
      double u = su[row][c];
      __hip_atomic_store(&hcG[(long)row*HH+col],
        (1.0-u)*sH[row][col] + u*nh, __ATOMIC_RELAXED, AGT);
    }
  };
  auto rgS = [&](){
    const int pc = lane&15, ks = lane>>4;
    const int pcol = colP0 + pc;
    const float* w = WMR + (long)(ks*128)*256 + pcol;
    const double* a = &sB[row][ks*128];
    double o=0,o2=0;
    #pragma unroll 8
    for (int k=0;k<128;k+=2){
      int ka = (k   + (ks<<2)) & 127;
      int kb = (k+1 + (ks<<2)) & 127;
      o  = fma(a[ka],(double)w[(long)ka*256],o);
      o2 = fma(a[kb],(double)w[(long)kb*256],o2);
    }
    o += o2; o += __shfl_xor(o,16); o += __shfl_xor(o,32);
    if (lane<16){
      __hip_atomic_store(&moG[(long)row*PP+pcol],
        sigd(o + (double)bmr_[pcol]) * sm[row][pc], __ATOMIC_RELAXED, AGT);
    }
  };
  auto hmS = [&](int t){
    const int c = lane&31, ks = lane>>5;
    const int col = colH0 + c;
    const float* w = WMH + (long)(ks*128)*512 + col;
    const double* a = &sM[row][ks*128];
    double o=0,o2=0;
    #pragma unroll 8
    for (int k=0;k<128;k+=2){
      o  = fma(a[k],  (double)w[(long)k*512],    o);
      o2 = fma(a[k+1],(double)w[(long)(k+1)*512],o2);
    }
    o += o2; o += __shfl_xor(o,32);
    if (lane<32){
      double hv = o + (double)bmh_[col] + sB[row][col];
      long gi = (long)(r0g+row)*HH + col;
      if (lay==0){
        __hip_atomic_store(&g_h0d[(long)(t&1)*BB*HH + gi], hv, __ATOMIC_RELAXED, AGT);
      } else {
        __hip_atomic_store(&g_h1[gi], hv, __ATOMIC_RELAXED, AGT);
        __builtin_nontemporal_store(hv, &g_hist[((long)(r0g+row)*TT + t)*HH + col]);
      }
    }
  };

  for (int t=0; t<TT; ++t){
    // St1: ru (+ deferred mg(t-1), A = h_mem(t-1) = sH)
    if (lay==0){
      ldX(t);
      ld512(sH, &g_h0d[(long)((t+1)&1)*BB*HH + (long)r0g*HH]);
    } else {
      wait_ge(0,3,(unsigned)(t+1));                 // h_mem0(t) ready
      ld512(sP, &g_h0d[(long)(t&1)*BB*HH + (long)r0g*HH]);
      ld512(sH, g_h1 + (long)r0g*HH);
    }
    __syncthreads();
    ruS();
    if (t>0) mgS();
    bar(0);                                          // L1's gen here = consumer progress
    // St2: n -> h_cand
    ld512(sB, rhG);
    __syncthreads();
    nS();
    bar(1);
    // St3: read gate -> mem_out
    ld512(sB, hcG);
    __syncthreads();
    rgS();
    bar(2);
    // St4: h_mem (sB = hc kept)
    ld256(moG);
    __syncthreads();
    if (lay==0 && t>=2) wait_ge(1,0,(unsigned)(t-1)); // back-pressure on h0 buffer
    hmS(t);
    bar(3);                                          // L0's gen here = producer progress
  }

  // deferred mg flush for t = TT-1
  if (lay==0) ld512(sH, &g_h0d[(long)((TT-1)&1)*BB*HH + (long)r0g*HH]);
  else        ld512(sH, g_h1 + (long)r0g*HH);
  __syncthreads();
  mgS();
  __syncthreads();

  // finals appended after outputs, FP32: h_final [2,B,H], m_final [2,B,P]
  const long ob = (long)BB*TT*OO;
  if (tid < 256){
    int r = tid>>5, c = tid&31; int col = colH0 + c; long bq = r0g + r;
    p.out[ob + (long)lay*BB*HH + bq*HH + col] = (float)sH[r][col];
  }
  if (tid < 128){
    int r = tid>>4, pc = tid&15; int pcol = colP0 + pc; long bq = r0g + r;
    p.out[ob + 2L*BB*HH + (long)lay*BB*PP + bq*PP + pcol] = (float)sm[r][pc];
  }
}

// outputs[b,t,:] = Wout @ h_mem1[b,t,:] + bout — LDS-staged hist rows, transposed Wout
__global__ void __launch_bounds__(512) out_gemm(const float* bout, float* out)
{
  __shared__ double sH[8][512];
  const int tid = threadIdx.x;
  const int iw = tid >> 6, lane = tid & 63;
  const int kq = lane >> 5, c32 = lane & 31;
  const int col = iw*64 + c32*2;
  const float* w = g_WoutT + kq*(256*512) + col;
  for (int rbx = blockIdx.x; rbx < BB*TT/8; rbx += gridDim.x){
    __syncthreads();
    for (int i = tid; i < 8*256; i += 512){
      int rr = i >> 8, c2 = (i & 255) << 1;
      *(double2*)&sH[rr][c2] = *(const double2*)(g_hist + (long)(rbx*8+rr)*HH + c2);
    }
    __syncthreads();
    double s[8][2];
    #pragma unroll
    for (int r=0;r<8;++r){ s[r][0]=0.0; s[r][1]=0.0; }
    #pragma unroll 2
    for (int k=0;k<256;++k){
      float2 wv = *(const float2*)(w + (long)k*512);
      double wx = (double)wv.x, wy = (double)wv.y;
      #pragma unroll
      for (int r=0;r<8;++r){
        double av = sH[r][kq*256 + k];
        s[r][0] = fma(av, wx, s[r][0]);
        s[r][1] = fma(av, wy, s[r][1]);
      }
    }
    #pragma unroll
    for (int r=0;r<8;++r){
      double t0 = s[r][0] + __shfl_xor(s[r][0],32);
      double t1 = s[r][1] + __shfl_xor(s[r][1],32);
      if (lane < 32){
        float2 fv;
        fv.x = (float)(t0 + (double)bout[col]);
        fv.y = (float)(t1 + (double)bout[col+1]);
        *(float2*)&out[(long)(rbx*8+r)*OO + col] = fv;
      }
    }
  }
}

extern "C" void kernel_launch(void* const* d_in, const int* in_sizes, int n_in,
                              void* d_out, int out_size, void* d_ws, size_t ws_size,
                              hipStream_t stream)
{
  KP p;
  p.x   = (const float*)d_in[0];
  p.Wr  = (const float*)d_in[1];  p.br  = (const float*)d_in[2];
  p.Wu  = (const float*)d_in[3];  p.bu  = (const float*)d_in[4];
  p.Wn  = (const float*)d_in[5];  p.bn  = (const float*)d_in[6];
  p.Wmr = (const float*)d_in[7];  p.bmr = (const float*)d_in[8];
  p.Wmw = (const float*)d_in[9];  p.bmw = (const float*)d_in[10];
  p.Wmu = (const float*)d_in[11]; p.bmu = (const float*)d_in[12];
  p.Wmh = (const float*)d_in[13]; p.bmh = (const float*)d_in[14];
  p.Wd  = (const float*)d_in[15]; p.bd  = (const float*)d_in[16];
  p.Ws  = (const float*)d_in[17]; p.bs  = (const float*)d_in[18];
  p.Wout= (const float*)d_in[19]; p.bout= (const float*)d_in[20];
  p.dop = (const float*)d_in[21]; p.ser = (const float*)d_in[22];
  p.out = (float*)d_out;

  prep<<<dim3(5120), dim3(256), 0, stream>>>(p);
  rnn_kernel<<<dim3(256), dim3(NTHR), 0, stream>>>(p);
  out_gemm<<<dim3(2048), dim3(512), 0, stream>>>(p.bout, p.out);
}